// Round 12
// baseline (410.521 us; speedup 1.0000x reference)
//
#include <hip/hip_runtime.h>
#include <hip/hip_bf16.h>

typedef unsigned short u16;
typedef unsigned char  u8;
typedef unsigned int   u32;
typedef __attribute__((ext_vector_type(8))) short short8;
typedef __attribute__((ext_vector_type(4))) float floatx4;
typedef __attribute__((ext_vector_type(2))) float floatx2;

__device__ __forceinline__ float bits2f(u32 v){ float f; __builtin_memcpy(&f, &v, 4); return f; }
__device__ __forceinline__ u16 f2bf(float f){
    __hip_bfloat16 h = __float2bfloat16(f);
    u16 u; __builtin_memcpy(&u, &h, 2); return u;
}

// global -> LDS async DMA, 16 B per lane, dest = wave-uniform base + lane*16
__device__ __forceinline__ void gload_lds16(const void* g, void* l){
    __builtin_amdgcn_global_load_lds(
        (const __attribute__((address_space(1))) unsigned char*)g,
        (__attribute__((address_space(3))) unsigned char*)l, 16, 0, 0);
}

#define NBIN 32   // stat bins; per-address atomic depth bounded

// ---------------- prep: f32->bf16+fp8 convert  |  bucket hist  |  weight pack ----------------
// NOTE (r9/r10): prep's 40.28us is invariant under structural changes -> pinned by the
// harness's 262MB workspace-poison fill overlapping on HBM. Do not optimize further.

__global__ __launch_bounds__(256) void prep_kernel(const float* __restrict__ x,
                                                   u16* __restrict__ hbuf,
                                                   u32* __restrict__ x8, int total4, int nCvtB,
                                                   const int* __restrict__ dst,
                                                   int* __restrict__ gbcnt, int E, int nHistB,
                                                   const float* __restrict__ w0s, const float* __restrict__ w0n,
                                                   const float* __restrict__ w1s, const float* __restrict__ w1n,
                                                   const float* __restrict__ w2s, const float* __restrict__ w2n,
                                                   u16* __restrict__ bp0, u16* __restrict__ bp1,
                                                   u16* __restrict__ bp2){
    const int b = blockIdx.x;
    if (b < nCvtB){
        const int i0 = b * 256 + threadIdx.x;
        const int S  = nCvtB * 256;
        float4 v[4];
        #pragma unroll
        for (int u = 0; u < 4; ++u){
            const int idx = i0 + u * S;
            if (idx < total4) v[u] = ((const float4*)x)[idx];
        }
        #pragma unroll
        for (int u = 0; u < 4; ++u){
            const int idx = i0 + u * S;
            if (idx < total4){
                uint2 o;
                o.x = (u32)f2bf(v[u].x) | ((u32)f2bf(v[u].y) << 16);
                o.y = (u32)f2bf(v[u].z) | ((u32)f2bf(v[u].w) << 16);
                ((uint2*)hbuf)[idx] = o;
                u32 p8 = (u32)__builtin_amdgcn_cvt_pk_fp8_f32(v[u].x, v[u].y, 0, false);
                p8     = (u32)__builtin_amdgcn_cvt_pk_fp8_f32(v[u].z, v[u].w, (int)p8, true);
                x8[idx] = p8;
            }
        }
    } else if (b < nCvtB + nHistB){
        __shared__ int bc[256];
        const int t = threadIdx.x;
        bc[t] = 0;
        __syncthreads();
        const int tile0 = (b - nCvtB) * 8192;
        const int cnt = min(8192, E - tile0);
        for (int j = t; j < cnt; j += 256) atomicAdd(&bc[dst[tile0 + j] >> 9], 1);
        __syncthreads();
        if (bc[t] > 0) atomicAdd(&gbcnt[t], bc[t]);
    } else {
        int i = (b - nCvtB - nHistB) * 256 + threadIdx.x;   // 81920 exact
        const float *ws, *wn; u16* bp; int N;
        if (i < 32768){ ws = w0s; wn = w0n; bp = bp0; N = 128; }
        else if (i < 65536){ i -= 32768; ws = w1s; wn = w1n; bp = bp1; N = 128; }
        else { i -= 65536; ws = w2s; wn = w2n; bp = bp2; N = 64; }
        int n = i >> 8, k = i & 255;
        float v = (k < 128) ? ws[k * N + n] : wn[(k - 128) * N + n];
        bp[i] = f2bf(v);
    }
}

// ------- bf16 pre -> fp8 activated table: fp8(relu(pre*sc + sh)) -------
// BN finalize folded in: reduce NBIN binned channel sums, derive sc/sh per block.

__global__ __launch_bounds__(256) void cvt8a_kernel(const u16* __restrict__ in,
                                                    const float* __restrict__ cs,
                                                    const float* __restrict__ gamma,
                                                    const float* __restrict__ beta,
                                                    float invM,
                                                    uint2* __restrict__ out8, int total8){
    __shared__ float s_sc[128], s_sh[128];
    if (threadIdx.x < 128){
        const int c = threadIdx.x;
        float s = 0.f, q = 0.f;
        #pragma unroll
        for (int b = 0; b < NBIN; ++b){
            s += cs[b * 256 + c];
            q += cs[b * 256 + 128 + c];
        }
        float mu  = s * invM;
        float var = fmaxf(q * invM - mu * mu, 0.f);
        float sc  = gamma[c] * rsqrtf(var + 1e-5f);
        s_sc[c] = sc;
        s_sh[c] = beta[c] - mu * sc;
    }
    __syncthreads();
    int i = blockIdx.x * 256 + threadIdx.x;   // 8 bf16 per thread
    if (i >= total8) return;
    const int c0 = (i & 15) * 8;              // 128 channels per row, 16 threads/row
    uint4 v = ((const uint4*)in)[i];
    u32 w[4] = {v.x, v.y, v.z, v.w};
    float f[8];
    #pragma unroll
    for (int j = 0; j < 4; ++j){
        f[2*j]   = bits2f(w[j] << 16);
        f[2*j+1] = bits2f(w[j] & 0xffff0000u);
    }
    #pragma unroll
    for (int j = 0; j < 8; ++j)
        f[j] = fmaxf(fmaf(f[j], s_sc[c0 + j], s_sh[c0 + j]), 0.f);
    u32 lo = (u32)__builtin_amdgcn_cvt_pk_fp8_f32(f[0], f[1], 0, false);
    lo     = (u32)__builtin_amdgcn_cvt_pk_fp8_f32(f[2], f[3], (int)lo, true);
    u32 hi = (u32)__builtin_amdgcn_cvt_pk_fp8_f32(f[4], f[5], 0, false);
    hi     = (u32)__builtin_amdgcn_cvt_pk_fp8_f32(f[6], f[7], (int)hi, true);
    uint2 o; o.x = lo; o.y = hi;
    out8[i] = o;
}

// ---------------- CSR build: bucket scan -> multisplit bin -> bucket sort ----------------

__global__ __launch_bounds__(256) void bscan_kernel(const int* __restrict__ gbcnt,
                                                    int* __restrict__ bbase,
                                                    int* __restrict__ bcur, int nbuk){
    __shared__ int ws[4];
    const int t = threadIdx.x, lane = t & 63, wv = t >> 6;
    int v = (t < nbuk) ? gbcnt[t] : 0;
    int s = v;
    for (int off = 1; off < 64; off <<= 1){
        int n = __shfl_up(s, off);
        if (lane >= off) s += n;
    }
    if (lane == 63) ws[wv] = s;
    __syncthreads();
    int woff = 0;
    for (int w = 0; w < wv; ++w) woff += ws[w];
    int excl = s + woff - v;
    if (t < nbuk){ bbase[t] = excl; bcur[t] = excl; }
}

#define BIN_TILE 8192
__global__ __launch_bounds__(256) void bin_kernel(const int* __restrict__ src,
                                                  const int* __restrict__ dst,
                                                  int* __restrict__ bcur,
                                                  u32* __restrict__ pairs, int E, int nbuk){
    __shared__ u32 hcnt[256], hexcl[256], hoff[256];
    __shared__ int gbase[256];
    __shared__ u32 stage[BIN_TILE];
    __shared__ unsigned char bkt[BIN_TILE];
    const int t = threadIdx.x;
    const int tile0 = blockIdx.x * BIN_TILE;
    const int cntE = min(BIN_TILE, E - tile0);

    hcnt[t] = 0;
    __syncthreads();
    for (int j = t; j < cntE; j += 256){
        int d = dst[tile0 + j];
        atomicAdd(&hcnt[d >> 9], 1u);
    }
    __syncthreads();
    if (t < 64){
        u32 a0 = hcnt[4*t], a1 = hcnt[4*t+1], a2 = hcnt[4*t+2], a3 = hcnt[4*t+3];
        u32 lsum = a0 + a1 + a2 + a3;
        u32 s = lsum;
        for (int off = 1; off < 64; off <<= 1){
            u32 n = __shfl_up(s, off);
            if (t >= off) s += n;
        }
        u32 base = s - lsum;
        hexcl[4*t]   = base;
        hexcl[4*t+1] = base + a0;
        hexcl[4*t+2] = base + a0 + a1;
        hexcl[4*t+3] = base + a0 + a1 + a2;
        hoff[4*t]   = base;
        hoff[4*t+1] = base + a0;
        hoff[4*t+2] = base + a0 + a1;
        hoff[4*t+3] = base + a0 + a1 + a2;
    }
    __syncthreads();
    if (t < nbuk && hcnt[t] > 0) gbase[t] = atomicAdd(&bcur[t], (int)hcnt[t]);
    for (int j = t; j < cntE; j += 256){
        int d = dst[tile0 + j];
        int s = src[tile0 + j];
        int b = d >> 9;
        u32 p = atomicAdd(&hoff[b], 1u);
        stage[p] = ((u32)s << 9) | (u32)(d & 511);
        bkt[p] = (unsigned char)b;
    }
    __syncthreads();
    for (int j = t; j < cntE; j += 256){
        int b = bkt[j];
        pairs[gbase[b] + (int)((u32)j - hexcl[b])] = stage[j];
    }
}

__global__ __launch_bounds__(256) void sort2_kernel(const u32* __restrict__ pairs,
                                                    const int* __restrict__ bbase,
                                                    int* __restrict__ indptr,
                                                    float* __restrict__ invdeg,
                                                    int* __restrict__ esrc,
                                                    int* __restrict__ gdch,
                                                    int M, int E, int nbuk){
    __shared__ int ndeg[512];
    __shared__ int cur[512];
    __shared__ int wsI[4];
    __shared__ int dh[64];
    const int b = blockIdx.x;
    const int node0 = b * 512;
    const int lo = bbase[b];
    const int hi = (b + 1 < nbuk) ? bbase[b + 1] : E;
    const int t = threadIdx.x, lane = t & 63, wv = t >> 6;

    ndeg[t] = 0; ndeg[t + 256] = 0;
    if (t < 64) dh[t] = 0;
    __syncthreads();
    for (int i = lo + t; i < hi; i += 256) atomicAdd(&ndeg[pairs[i] & 511], 1);
    __syncthreads();

    const int d0 = ndeg[2*t], d1 = ndeg[2*t + 1];
    const int p = d0 + d1;
    int s = p;
    for (int off = 1; off < 64; off <<= 1){
        int n = __shfl_up(s, off);
        if (lane >= off) s += n;
    }
    if (lane == 63) wsI[wv] = s;
    __syncthreads();
    int woff = 0;
    for (int w = 0; w < wv; ++w) woff += wsI[w];
    const int incl = s + woff;
    const int excl0 = incl - p;
    const int excl1 = excl0 + d0;

    const int n0 = node0 + 2*t, n1 = node0 + 2*t + 1;
    if (n0 < M){
        indptr[n0 + 1] = lo + excl0 + d0;
        invdeg[n0] = 1.0f / (float)max(d0, 1);
        cur[2*t] = lo + excl0;
        atomicAdd(&dh[min(d0, 63)], 1);
    }
    if (n1 < M){
        indptr[n1 + 1] = lo + excl1 + d1;
        invdeg[n1] = 1.0f / (float)max(d1, 1);
        cur[2*t + 1] = lo + excl1;
        atomicAdd(&dh[min(d1, 63)], 1);
    }
    if (b == 0 && t == 0) indptr[0] = 0;
    __syncthreads();
    if (t < 64 && dh[t] > 0) atomicAdd(&gdch[t], dh[t]);
    for (int i = lo + t; i < hi; i += 256){
        u32 v = pairs[i];
        int pos = atomicAdd(&cur[v & 511], 1);
        esrc[pos] = (int)(v >> 9);
    }
}

// ---------------- degree-sorted node permutation (anti-divergence for agg) ----------------
// permscan: exclusive scan of the 64-class degree histogram -> class cursors.

__global__ __launch_bounds__(64) void permscan_kernel(const int* __restrict__ gdch,
                                                      int* __restrict__ dccur){
    const int t = threadIdx.x;  // 0..63
    int v = gdch[t];
    int s = v;
    for (int off = 1; off < 64; off <<= 1){
        int n = __shfl_up(s, off);
        if (t >= off) s += n;
    }
    dccur[t] = s - v;
}

// permscat: multisplit scatter (bin_kernel pattern), 8192 nodes/block, 2 passes.
#define PB_TILE 8192
__global__ __launch_bounds__(256) void permscat_kernel(const int* __restrict__ indptr,
                                                       int* __restrict__ dccur,
                                                       int* __restrict__ nodeperm, int M){
    __shared__ u32 h[64];
    __shared__ int gb[64];
    __shared__ u32 hcur[64];
    const int t = threadIdx.x;
    const int tile0 = blockIdx.x * PB_TILE;
    const int cnt = min(PB_TILE, M - tile0);
    if (t < 64) h[t] = 0;
    __syncthreads();
    for (int j = t; j < cnt; j += 256){
        const int n = tile0 + j;
        const int deg = indptr[n + 1] - indptr[n];
        atomicAdd(&h[min(deg, 63)], 1u);
    }
    __syncthreads();
    if (t < 64){
        gb[t] = (h[t] > 0) ? atomicAdd(&dccur[t], (int)h[t]) : 0;
        hcur[t] = 0;
    }
    __syncthreads();
    for (int j = t; j < cnt; j += 256){
        const int n = tile0 + j;
        const int deg = indptr[n + 1] - indptr[n];
        const int cls = min(deg, 63);
        u32 p = atomicAdd(&hcur[cls], 1u);
        nodeperm[gb[cls] + (int)p] = n;
    }
}

// ---------------- aggregation over fp8 table ----------------
// One 8-lane group per node (8 nodes/wave). Lane l8 owns 16 fp8 channels (16 B).
// Nodes processed in DEGREE-SORTED order (nodeperm): groups within a wave have
// near-equal degrees -> wave time = mean chunks, not max-of-8 (anti-divergence).
// 8-edge unroll: 8 independent gathers in flight per lane.

__global__ __launch_bounds__(256) void agg_kernel(const u8* __restrict__ h8,
                                                  const int* __restrict__ indptr,
                                                  const int* __restrict__ esrc,
                                                  const float* __restrict__ invdeg,
                                                  const int* __restrict__ nodeperm,
                                                  u16* __restrict__ agg, int M){
    const int l8 = threadIdx.x & 7;
    const int gid = (blockIdx.x * 256 + threadIdx.x) >> 3;
    if (gid >= M) return;
    const int n = nodeperm[gid];
    const int beg = indptr[n];
    const int end = indptr[n + 1];
    const float fs = invdeg[n];

    floatx2 acc[8];
    #pragma unroll
    for (int i = 0; i < 8; ++i){ acc[i].x = 0.f; acc[i].y = 0.f; }

    const u8* hb = h8 + l8 * 16;

    auto accum = [&](uint4 v){
        u32 w[4] = {v.x, v.y, v.z, v.w};
        #pragma unroll
        for (int j = 0; j < 4; ++j){
            acc[2*j]   += __builtin_amdgcn_cvt_pk_f32_fp8(w[j], false);
            acc[2*j+1] += __builtin_amdgcn_cvt_pk_f32_fp8(w[j], true);
        }
    };

    int e = beg;
    for (; e + 8 <= end; e += 8){
        int idx[8];
        #pragma unroll
        for (int u = 0; u < 8; ++u) idx[u] = esrc[e + u];
        uint4 v[8];
        #pragma unroll
        for (int u = 0; u < 8; ++u) v[u] = *(const uint4*)(hb + (size_t)idx[u] * 128);
        #pragma unroll
        for (int u = 0; u < 8; ++u) accum(v[u]);
    }
    if (e + 4 <= end){
        int idx[4];
        #pragma unroll
        for (int u = 0; u < 4; ++u) idx[u] = esrc[e + u];
        uint4 v[4];
        #pragma unroll
        for (int u = 0; u < 4; ++u) v[u] = *(const uint4*)(hb + (size_t)idx[u] * 128);
        #pragma unroll
        for (int u = 0; u < 4; ++u) accum(v[u]);
        e += 4;
    }
    for (; e < end; ++e){
        uint4 v0 = *(const uint4*)(hb + (size_t)esrc[e] * 128);
        accum(v0);
    }

    u32 o[8];
    #pragma unroll
    for (int k = 0; k < 8; ++k)
        o[k] = (u32)f2bf(acc[k].x * fs) | ((u32)f2bf(acc[k].y * fs) << 16);
    uint4 w0 = {o[0], o[1], o[2], o[3]};
    uint4 w1 = {o[4], o[5], o[6], o[7]};
    *(uint4*)(agg + (size_t)n * 128 + l8 * 16)     = w0;
    *(uint4*)(agg + (size_t)n * 128 + l8 * 16 + 8) = w1;
}

// ------- GEMM (r7-proven shape, best measured 381.5us): block-cooperative.
// A tile staged once via global_load_lds (k-major [k0][quad][row][16B], linear
// DMA dest, conflict-free b128 reads). 4 waves split output cols (NTW each).
// B in registers (AGPR half of unified file -> __launch_bounds__(256,4); do NOT
// raise: ~128 combined regs, higher bounds spill -- r6 lesson; 8-wave/NTW=1 and
// 32-row tiles both measured neutral-to-worse, r9/r11). 3-deep LDS ring, counted
// vmcnt 4/2/0, raw s_barrier. Single C staging buffer. STATS: binned atomic
// channel sums. AFFA: scale/shift from binned sums. LSM: fused log_softmax. -------

template<int NTW, bool STATS, bool AFFA, bool LSM>
__global__ __launch_bounds__(256, 4) void gemm3_kernel(const u16* __restrict__ hA,
                                                       const u16* __restrict__ aggA,
                                                       const u16* __restrict__ Bp,
                                                       const float* __restrict__ bias,
                                                       const float* __restrict__ cs,
                                                       const float* __restrict__ gammaA,
                                                       const float* __restrict__ betaA,
                                                       float invM,
                                                       void* __restrict__ outPre,
                                                       float* __restrict__ csOut,
                                                       int M, int T, int GBs){
    constexpr int N = NTW * 64;                 // output width (4 waves x NTW x 16)
    __shared__ __align__(16) u16 Abuf[3][4096]; // 3 x 8KB A tiles, [k0][quad][row][8 u16]
    __shared__ __align__(16) char cbuf[4352];   // C staging (u16 stride 136 / f32 stride 68)
    __shared__ float s_sc[128], s_sh[128];

    const int wave = threadIdx.x >> 6;
    const int lane = threadIdx.x & 63;
    const int m15 = lane & 15;
    const int quad = lane >> 4;
    const int colbase = wave * (NTW * 16);

    if (AFFA && threadIdx.x < 128){
        const int c = threadIdx.x;
        float s = 0.f, q = 0.f;
        #pragma unroll
        for (int b = 0; b < NBIN; ++b){
            s += cs[b * 256 + c];
            q += cs[b * 256 + 128 + c];
        }
        float mu  = s * invM;
        float var = fmaxf(q * invM - mu * mu, 0.f);
        float sc  = gammaA[c] * rsqrtf(var + 1e-5f);
        s_sc[c] = sc;
        s_sh[c] = betaA[c] - mu * sc;
    }
    __syncthreads();   // once, before any prefetch is in flight

    short8 breg[NTW][8];
    float bv[NTW];
    #pragma unroll
    for (int nt = 0; nt < NTW; ++nt){
        bv[nt] = bias[colbase + nt * 16 + m15];
        #pragma unroll
        for (int k0 = 0; k0 < 8; ++k0)
            breg[nt][k0] = *(const short8*)(Bp + (size_t)(colbase + nt * 16 + m15) * 256 + k0 * 32 + quad * 8);
    }

    float sS[NTW], sQ[NTW];
    #pragma unroll
    for (int nt = 0; nt < NTW; ++nt){ sS[nt] = 0.f; sQ[nt] = 0.f; }

    // wave w stages k0 = 2w, 2w+1 (2 x 1KB DMA per wave per tile)
    auto stage = [&](int bufIdx, int tile){
        const int srow = lane & 15, squad = lane >> 4;
        int arow = tile * 16 + srow;
        if (arow >= M) arow = M - 1;
        #pragma unroll
        for (int h = 0; h < 2; ++h){
            const int k0 = wave * 2 + h;
            const u16* base = (k0 < 4) ? hA : aggA;
            const u16* g = base + (size_t)arow * 128 + (k0 & 3) * 32 + squad * 8;
            gload_lds16(g, &Abuf[bufIdx][k0 * 512]);
        }
    };

    const int t0 = blockIdx.x;
    const int nIter = (T - 1 - t0) / GBs + 1;

    stage(0, t0);
    if (nIter > 1) stage(1, t0 + GBs);

    int t = t0;
    for (int it = 0; it < nIter; ++it){
        const int cur = it % 3;
        if (it + 2 < nIter) stage((it + 2) % 3, t + 2 * GBs);

        const int ahead = min(nIter - 1 - it, 2);
        if (ahead >= 2)      asm volatile("s_waitcnt vmcnt(4)" ::: "memory");
        else if (ahead == 1) asm volatile("s_waitcnt vmcnt(2)" ::: "memory");
        else                 asm volatile("s_waitcnt vmcnt(0)" ::: "memory");
        __builtin_amdgcn_s_barrier();
        __builtin_amdgcn_sched_barrier(0);

        floatx4 acc[NTW];
        #pragma unroll
        for (int nt = 0; nt < NTW; ++nt) acc[nt] = 0.0f;
        #pragma unroll
        for (int k0 = 0; k0 < 8; ++k0){
            short8 a = *(const short8*)&Abuf[cur][k0 * 512 + quad * 128 + m15 * 8];
            if (AFFA && k0 < 4){
                const int cb = k0 * 32 + quad * 8;
                #pragma unroll
                for (int j = 0; j < 8; ++j){
                    float f = bits2f(((u32)(u16)a[j]) << 16);
                    f = fmaxf(fmaf(f, s_sc[cb + j], s_sh[cb + j]), 0.f);
                    a[j] = (short)f2bf(f);
                }
            }
            #pragma unroll
            for (int nt = 0; nt < NTW; ++nt)
                acc[nt] = __builtin_amdgcn_mfma_f32_16x16x32_bf16(a, breg[nt][k0], acc[nt], 0, 0, 0);
        }

        // ---- epilogue: bias (+stats), stage C tile in LDS ----
        const int r0 = quad * 4;
        #pragma unroll
        for (int nt = 0; nt < NTW; ++nt){
            const int col = colbase + nt * 16 + m15;
            #pragma unroll
            for (int r = 0; r < 4; ++r){
                float v = acc[nt][r] + bv[nt];
                if (STATS){
                    int row = t * 16 + r0 + r;
                    if (row < M){
                        sS[nt] += v;
                        sQ[nt] = fmaf(v, v, sQ[nt]);
                    }
                    ((u16*)cbuf)[(r0 + r) * 136 + col] = f2bf(v);
                } else {
                    ((float*)cbuf)[(r0 + r) * 68 + col] = v;
                }
            }
        }
        asm volatile("s_waitcnt lgkmcnt(0)" ::: "memory");
        __builtin_amdgcn_s_barrier();          // C visible; also fences Abuf[cur] reuse
        __builtin_amdgcn_sched_barrier(0);

        const int srow = threadIdx.x >> 4, seg = threadIdx.x & 15;
        const int grow = t * 16 + srow;
        if (LSM){
            // full 64-wide row is held by the 16 threads seg=0..15 of this srow
            float4 w = *(const float4*)((const float*)cbuf + srow * 68 + seg * 4);
            float m = fmaxf(fmaxf(w.x, w.y), fmaxf(w.z, w.w));
            m = fmaxf(m, __shfl_xor(m, 1));
            m = fmaxf(m, __shfl_xor(m, 2));
            m = fmaxf(m, __shfl_xor(m, 4));
            m = fmaxf(m, __shfl_xor(m, 8));
            float e = __expf(w.x - m) + __expf(w.y - m) + __expf(w.z - m) + __expf(w.w - m);
            e += __shfl_xor(e, 1);
            e += __shfl_xor(e, 2);
            e += __shfl_xor(e, 4);
            e += __shfl_xor(e, 8);
            float lg = m + __logf(e);
            if (grow < M){
                float4 o;
                o.x = w.x - lg; o.y = w.y - lg; o.z = w.z - lg; o.w = w.w - lg;
                *(float4*)((float*)outPre + (size_t)grow * 64 + seg * 4) = o;
            }
        } else if (grow < M){
            if (STATS){
                uint4 w = *(const uint4*)((const u16*)cbuf + srow * 136 + seg * 8);
                *(uint4*)((u16*)outPre + (size_t)grow * N + seg * 8) = w;
            } else {
                float4 w = *(const float4*)((const float*)cbuf + srow * 68 + seg * 4);
                *(float4*)((float*)outPre + (size_t)grow * N + seg * 4) = w;
            }
        }
        t += GBs;
    }

    if (STATS){
        const int binoff = (blockIdx.x & (NBIN - 1)) * 256;
        #pragma unroll
        for (int nt = 0; nt < NTW; ++nt){
            float s = sS[nt], q = sQ[nt];
            s += __shfl_xor(s, 16);  s += __shfl_xor(s, 32);
            q += __shfl_xor(q, 16);  q += __shfl_xor(q, 32);
            if (quad == 0){
                const int c = colbase + nt * 16 + m15;
                atomicAdd(&csOut[binoff + c], s);
                atomicAdd(&csOut[binoff + 128 + c], q);
            }
        }
    }
}

// ---------------- host ----------------

extern "C" void kernel_launch(void* const* d_in, const int* in_sizes, int n_in,
                              void* d_out, int out_size, void* d_ws, size_t ws_size,
                              hipStream_t stream) {
    const float* x   = (const float*)d_in[0];
    const int*   src = (const int*)d_in[1];
    const int*   dst = (const int*)d_in[2];
    const float* wself[3]  = {(const float*)d_in[3], (const float*)d_in[6], (const float*)d_in[9]};
    const float* wneigh[3] = {(const float*)d_in[4], (const float*)d_in[7], (const float*)d_in[10]};
    const float* bias[3]   = {(const float*)d_in[5], (const float*)d_in[8], (const float*)d_in[11]};
    const float* gamma[2]  = {(const float*)d_in[12], (const float*)d_in[14]};
    const float* beta[2]   = {(const float*)d_in[13], (const float*)d_in[15]};

    const int M = in_sizes[0] / 128;   // 100000
    const int E = in_sizes[1];         // 1600000
    const int NBUK = (M + 511) / 512;  // 196
    const int T = (M + 15) / 16;       // 6250 A-tiles
    const int GB = 1024;               // proven grid (r7: 381.5us)
    const float invM = 1.0f / (float)M;

    char* ws = (char*)d_ws;
    size_t off = 0;
    auto alloc = [&](size_t bytes) -> void* {
        void* p = ws + off;
        off = (off + bytes + 511) & ~(size_t)511;
        return p;
    };
    // zero-init region first (single memset): gbcnt + degree-class hist + binned colstat0/1
    int*   gbcnt    = (int*)alloc(256 * 4);
    int*   gdch     = (int*)alloc(64 * 4);
    float* colstat0 = (float*)alloc(NBIN * 256 * 4);
    float* colstat1 = (float*)alloc(NBIN * 256 * 4);
    const size_t zbytes = off;
    int*   dccur  = (int*)alloc(64 * 4);
    int*   bbase  = (int*)alloc(256 * 4);
    int*   bcur   = (int*)alloc(256 * 4);
    int*   indptr = (int*)alloc((size_t)(M + 1) * 4);
    u32*   pairs  = (u32*)alloc((size_t)E * 4);
    int*   esrc   = (int*)alloc((size_t)E * 4);
    float* invdeg = (float*)alloc((size_t)M * 4);
    int*   nodeperm = (int*)alloc((size_t)M * 4);
    u16* bpack0 = (u16*)alloc(128 * 256 * 2);
    u16* bpack1 = (u16*)alloc(128 * 256 * 2);
    u16* bpack2 = (u16*)alloc(64 * 256 * 2);
    u16*   hbuf   = (u16*)alloc((size_t)M * 128 * 2);   // bf16(x)
    u16*   aggbuf = (u16*)alloc((size_t)M * 128 * 2);
    u16*   preA   = (u16*)alloc((size_t)M * 128 * 2);   // layer0 pre-BN (bf16)
    u16*   preB   = (u16*)alloc((size_t)M * 128 * 2);   // layer1 pre-BN (bf16)
    u8*    x8     = (u8*)alloc((size_t)M * 128);        // fp8 gather tables (activated for L1/L2)
    u8*    preA8  = (u8*)alloc((size_t)M * 128);
    u8*    preB8  = (u8*)alloc((size_t)M * 128);

    hipMemsetAsync(ws, 0, zbytes, stream);

    // --- prep (cvt + bhist + pack3 in one launch; cvt does 4 float4/thread) ---
    const int total4 = M * 32;                      // 3,200,000 float4s
    const int nCvtB  = (total4 + 1023) / 1024;      // 3125 (4 per thread)
    const int nHistB = (E + 8191) / 8192;           // 196
    prep_kernel<<<nCvtB + nHistB + 320, 256, 0, stream>>>(
        x, hbuf, (u32*)x8, total4, nCvtB,
        dst, gbcnt, E, nHistB,
        wself[0], wneigh[0], wself[1], wneigh[1], wself[2], wneigh[2],
        bpack0, bpack1, bpack2);

    // --- CSR build + degree-sorted node permutation ---
    bscan_kernel<<<1, 256, 0, stream>>>(gbcnt, bbase, bcur, NBUK);
    bin_kernel<<<(E + BIN_TILE - 1) / BIN_TILE, 256, 0, stream>>>(src, dst, bcur, pairs, E, NBUK);
    sort2_kernel<<<NBUK, 256, 0, stream>>>(pairs, bbase, indptr, invdeg, esrc, gdch, M, E, NBUK);
    permscan_kernel<<<1, 64, 0, stream>>>(gdch, dccur);
    permscat_kernel<<<(M + PB_TILE - 1) / PB_TILE, 256, 0, stream>>>(indptr, dccur, nodeperm, M);

    // --- layer 0 ---
    agg_kernel<<<(M + 31) / 32, 256, 0, stream>>>(x8, indptr, esrc, invdeg, nodeperm, aggbuf, M);
    gemm3_kernel<2, true, false, false><<<GB, 256, 0, stream>>>(hbuf, aggbuf, bpack0, bias[0],
                                                                nullptr, nullptr, nullptr, invM,
                                                                preA, colstat0, M, T, GB);
    cvt8a_kernel<<<(M * 16 + 255) / 256, 256, 0, stream>>>(preA, colstat0, gamma[0], beta[0], invM,
                                                           (uint2*)preA8, M * 16);

    // --- layer 1 (fp8 table already activated; agg is affine-free) ---
    agg_kernel<<<(M + 31) / 32, 256, 0, stream>>>(preA8, indptr, esrc, invdeg, nodeperm, aggbuf, M);
    gemm3_kernel<2, true, true, false><<<GB, 256, 0, stream>>>(preA, aggbuf, bpack1, bias[1],
                                                               colstat0, gamma[0], beta[0], invM,
                                                               preB, colstat1, M, T, GB);
    cvt8a_kernel<<<(M * 16 + 255) / 256, 256, 0, stream>>>(preB, colstat1, gamma[1], beta[1], invM,
                                                           (uint2*)preB8, M * 16);

    // --- layer 2 (log_softmax fused into gemm epilogue) ---
    agg_kernel<<<(M + 31) / 32, 256, 0, stream>>>(preB8, indptr, esrc, invdeg, nodeperm, aggbuf, M);
    gemm3_kernel<1, false, true, true><<<GB, 256, 0, stream>>>(preB, aggbuf, bpack2, bias[2],
                                                               colstat1, gamma[1], beta[1], invM,
                                                               d_out, nullptr, M, T, GB);
}

// Round 13
// 380.217 us; speedup vs baseline: 1.0797x; 1.0797x over previous
//
#include <hip/hip_runtime.h>
#include <hip/hip_bf16.h>

typedef unsigned short u16;
typedef unsigned char  u8;
typedef unsigned int   u32;
typedef __attribute__((ext_vector_type(8))) short short8;
typedef __attribute__((ext_vector_type(4))) float floatx4;
typedef __attribute__((ext_vector_type(2))) float floatx2;

__device__ __forceinline__ float bits2f(u32 v){ float f; __builtin_memcpy(&f, &v, 4); return f; }
__device__ __forceinline__ u16 f2bf(float f){
    __hip_bfloat16 h = __float2bfloat16(f);
    u16 u; __builtin_memcpy(&u, &h, 2); return u;
}

// global -> LDS async DMA, 16 B per lane, dest = wave-uniform base + lane*16
__device__ __forceinline__ void gload_lds16(const void* g, void* l){
    __builtin_amdgcn_global_load_lds(
        (const __attribute__((address_space(1))) unsigned char*)g,
        (__attribute__((address_space(3))) unsigned char*)l, 16, 0, 0);
}

#define NBIN 16   // stat bins to spread atomic contention

// ---------------- prep: f32->bf16+fp8 convert  |  bucket hist  |  weight pack ----------------

__global__ __launch_bounds__(256) void prep_kernel(const float* __restrict__ x,
                                                   u16* __restrict__ hbuf,
                                                   u32* __restrict__ x8, int total4, int nCvtB,
                                                   const int* __restrict__ dst,
                                                   int* __restrict__ gbcnt, int E, int nHistB,
                                                   const float* __restrict__ w0s, const float* __restrict__ w0n,
                                                   const float* __restrict__ w1s, const float* __restrict__ w1n,
                                                   const float* __restrict__ w2s, const float* __restrict__ w2n,
                                                   u16* __restrict__ bp0, u16* __restrict__ bp1,
                                                   u16* __restrict__ bp2){
    const int b = blockIdx.x;
    if (b < nCvtB){
        int i = b * 256 + threadIdx.x;   // 4 floats per thread
        if (i >= total4) return;
        float4 v = ((const float4*)x)[i];
        uint2 o;
        o.x = (u32)f2bf(v.x) | ((u32)f2bf(v.y) << 16);
        o.y = (u32)f2bf(v.z) | ((u32)f2bf(v.w) << 16);
        ((uint2*)hbuf)[i] = o;
        u32 p8 = (u32)__builtin_amdgcn_cvt_pk_fp8_f32(v.x, v.y, 0, false);
        p8     = (u32)__builtin_amdgcn_cvt_pk_fp8_f32(v.z, v.w, (int)p8, true);
        x8[i] = p8;
    } else if (b < nCvtB + nHistB){
        __shared__ int bc[256];
        const int t = threadIdx.x;
        bc[t] = 0;
        __syncthreads();
        const int tile0 = (b - nCvtB) * 8192;
        const int cnt = min(8192, E - tile0);
        for (int j = t; j < cnt; j += 256) atomicAdd(&bc[dst[tile0 + j] >> 9], 1);
        __syncthreads();
        if (bc[t] > 0) atomicAdd(&gbcnt[t], bc[t]);
    } else {
        int i = (b - nCvtB - nHistB) * 256 + threadIdx.x;   // 81920 exact
        const float *ws, *wn; u16* bp; int N;
        if (i < 32768){ ws = w0s; wn = w0n; bp = bp0; N = 128; }
        else if (i < 65536){ i -= 32768; ws = w1s; wn = w1n; bp = bp1; N = 128; }
        else { i -= 65536; ws = w2s; wn = w2n; bp = bp2; N = 64; }
        int n = i >> 8, k = i & 255;
        float v = (k < 128) ? ws[k * N + n] : wn[(k - 128) * N + n];
        bp[i] = f2bf(v);
    }
}

// ------- bf16 pre -> fp8 activated table: fp8(relu(pre*sc + sh)) -------
// BN finalize folded in: reduce NBIN binned channel sums, derive sc/sh per block.

__global__ __launch_bounds__(256) void cvt8a_kernel(const u16* __restrict__ in,
                                                    const float* __restrict__ cs,
                                                    const float* __restrict__ gamma,
                                                    const float* __restrict__ beta,
                                                    float invM,
                                                    uint2* __restrict__ out8, int total8){
    __shared__ float s_sc[128], s_sh[128];
    if (threadIdx.x < 128){
        const int c = threadIdx.x;
        float s = 0.f, q = 0.f;
        #pragma unroll
        for (int b = 0; b < NBIN; ++b){
            s += cs[b * 256 + c];
            q += cs[b * 256 + 128 + c];
        }
        float mu  = s * invM;
        float var = fmaxf(q * invM - mu * mu, 0.f);
        float sc  = gamma[c] * rsqrtf(var + 1e-5f);
        s_sc[c] = sc;
        s_sh[c] = beta[c] - mu * sc;
    }
    __syncthreads();
    int i = blockIdx.x * 256 + threadIdx.x;   // 8 bf16 per thread
    if (i >= total8) return;
    const int c0 = (i & 15) * 8;              // 128 channels per row, 16 threads/row
    uint4 v = ((const uint4*)in)[i];
    u32 w[4] = {v.x, v.y, v.z, v.w};
    float f[8];
    #pragma unroll
    for (int j = 0; j < 4; ++j){
        f[2*j]   = bits2f(w[j] << 16);
        f[2*j+1] = bits2f(w[j] & 0xffff0000u);
    }
    #pragma unroll
    for (int j = 0; j < 8; ++j)
        f[j] = fmaxf(fmaf(f[j], s_sc[c0 + j], s_sh[c0 + j]), 0.f);
    u32 lo = (u32)__builtin_amdgcn_cvt_pk_fp8_f32(f[0], f[1], 0, false);
    lo     = (u32)__builtin_amdgcn_cvt_pk_fp8_f32(f[2], f[3], (int)lo, true);
    u32 hi = (u32)__builtin_amdgcn_cvt_pk_fp8_f32(f[4], f[5], 0, false);
    hi     = (u32)__builtin_amdgcn_cvt_pk_fp8_f32(f[6], f[7], (int)hi, true);
    uint2 o; o.x = lo; o.y = hi;
    out8[i] = o;
}

// ---------------- CSR build: bucket scan -> multisplit bin -> bucket sort ----------------

__global__ __launch_bounds__(256) void bscan_kernel(const int* __restrict__ gbcnt,
                                                    int* __restrict__ bbase,
                                                    int* __restrict__ bcur, int nbuk){
    __shared__ int ws[4];
    const int t = threadIdx.x, lane = t & 63, wv = t >> 6;
    int v = (t < nbuk) ? gbcnt[t] : 0;
    int s = v;
    for (int off = 1; off < 64; off <<= 1){
        int n = __shfl_up(s, off);
        if (lane >= off) s += n;
    }
    if (lane == 63) ws[wv] = s;
    __syncthreads();
    int woff = 0;
    for (int w = 0; w < wv; ++w) woff += ws[w];
    int excl = s + woff - v;
    if (t < nbuk){ bbase[t] = excl; bcur[t] = excl; }
}

#define BIN_TILE 8192
__global__ __launch_bounds__(256) void bin_kernel(const int* __restrict__ src,
                                                  const int* __restrict__ dst,
                                                  int* __restrict__ bcur,
                                                  u32* __restrict__ pairs, int E, int nbuk){
    __shared__ u32 hcnt[256], hexcl[256], hoff[256];
    __shared__ int gbase[256];
    __shared__ u32 stage[BIN_TILE];
    __shared__ unsigned char bkt[BIN_TILE];
    const int t = threadIdx.x;
    const int tile0 = blockIdx.x * BIN_TILE;
    const int cntE = min(BIN_TILE, E - tile0);

    hcnt[t] = 0;
    __syncthreads();
    for (int j = t; j < cntE; j += 256){
        int d = dst[tile0 + j];
        atomicAdd(&hcnt[d >> 9], 1u);
    }
    __syncthreads();
    if (t < 64){
        u32 a0 = hcnt[4*t], a1 = hcnt[4*t+1], a2 = hcnt[4*t+2], a3 = hcnt[4*t+3];
        u32 lsum = a0 + a1 + a2 + a3;
        u32 s = lsum;
        for (int off = 1; off < 64; off <<= 1){
            u32 n = __shfl_up(s, off);
            if (t >= off) s += n;
        }
        u32 base = s - lsum;
        hexcl[4*t]   = base;
        hexcl[4*t+1] = base + a0;
        hexcl[4*t+2] = base + a0 + a1;
        hexcl[4*t+3] = base + a0 + a1 + a2;
        hoff[4*t]   = base;
        hoff[4*t+1] = base + a0;
        hoff[4*t+2] = base + a0 + a1;
        hoff[4*t+3] = base + a0 + a1 + a2;
    }
    __syncthreads();
    if (t < nbuk && hcnt[t] > 0) gbase[t] = atomicAdd(&bcur[t], (int)hcnt[t]);
    for (int j = t; j < cntE; j += 256){
        int d = dst[tile0 + j];
        int s = src[tile0 + j];
        int b = d >> 9;
        u32 p = atomicAdd(&hoff[b], 1u);
        stage[p] = ((u32)s << 9) | (u32)(d & 511);
        bkt[p] = (unsigned char)b;
    }
    __syncthreads();
    for (int j = t; j < cntE; j += 256){
        int b = bkt[j];
        pairs[gbase[b] + (int)((u32)j - hexcl[b])] = stage[j];
    }
}

__global__ __launch_bounds__(256) void sort2_kernel(const u32* __restrict__ pairs,
                                                    const int* __restrict__ bbase,
                                                    int* __restrict__ indptr,
                                                    float* __restrict__ invdeg,
                                                    int* __restrict__ esrc,
                                                    int M, int E, int nbuk){
    __shared__ int ndeg[512];
    __shared__ int cur[512];
    __shared__ int wsI[4];
    const int b = blockIdx.x;
    const int node0 = b * 512;
    const int lo = bbase[b];
    const int hi = (b + 1 < nbuk) ? bbase[b + 1] : E;
    const int t = threadIdx.x, lane = t & 63, wv = t >> 6;

    ndeg[t] = 0; ndeg[t + 256] = 0;
    __syncthreads();
    for (int i = lo + t; i < hi; i += 256) atomicAdd(&ndeg[pairs[i] & 511], 1);
    __syncthreads();

    const int d0 = ndeg[2*t], d1 = ndeg[2*t + 1];
    const int p = d0 + d1;
    int s = p;
    for (int off = 1; off < 64; off <<= 1){
        int n = __shfl_up(s, off);
        if (lane >= off) s += n;
    }
    if (lane == 63) wsI[wv] = s;
    __syncthreads();
    int woff = 0;
    for (int w = 0; w < wv; ++w) woff += wsI[w];
    const int incl = s + woff;
    const int excl0 = incl - p;
    const int excl1 = excl0 + d0;

    const int n0 = node0 + 2*t, n1 = node0 + 2*t + 1;
    if (n0 < M){
        indptr[n0 + 1] = lo + excl0 + d0;
        invdeg[n0] = 1.0f / (float)max(d0, 1);
        cur[2*t] = lo + excl0;
    }
    if (n1 < M){
        indptr[n1 + 1] = lo + excl1 + d1;
        invdeg[n1] = 1.0f / (float)max(d1, 1);
        cur[2*t + 1] = lo + excl1;
    }
    if (b == 0 && t == 0) indptr[0] = 0;
    __syncthreads();
    for (int i = lo + t; i < hi; i += 256){
        u32 v = pairs[i];
        int pos = atomicAdd(&cur[v & 511], 1);
        esrc[pos] = (int)(v >> 9);
    }
}

// ---------------- aggregation over fp8 table ----------------
// One 8-lane group per node (8 nodes/wave). Lane l8 owns 16 fp8 channels (16 B).
// 8-edge unroll: 8 independent gathers in flight per lane to cover L2/L3 latency.

__global__ __launch_bounds__(256) void agg_kernel(const u8* __restrict__ h8,
                                                  const int* __restrict__ indptr,
                                                  const int* __restrict__ esrc,
                                                  const float* __restrict__ invdeg,
                                                  u16* __restrict__ agg, int M){
    const int l8 = threadIdx.x & 7;
    const int n = (blockIdx.x * 256 + threadIdx.x) >> 3;
    if (n >= M) return;
    const int beg = indptr[n];
    const int end = indptr[n + 1];
    const float fs = invdeg[n];

    floatx2 acc[8];
    #pragma unroll
    for (int i = 0; i < 8; ++i){ acc[i].x = 0.f; acc[i].y = 0.f; }

    const u8* hb = h8 + l8 * 16;

    auto accum = [&](uint4 v){
        u32 w[4] = {v.x, v.y, v.z, v.w};
        #pragma unroll
        for (int j = 0; j < 4; ++j){
            acc[2*j]   += __builtin_amdgcn_cvt_pk_f32_fp8(w[j], false);
            acc[2*j+1] += __builtin_amdgcn_cvt_pk_f32_fp8(w[j], true);
        }
    };

    int e = beg;
    for (; e + 8 <= end; e += 8){
        int idx[8];
        #pragma unroll
        for (int u = 0; u < 8; ++u) idx[u] = esrc[e + u];
        uint4 v[8];
        #pragma unroll
        for (int u = 0; u < 8; ++u) v[u] = *(const uint4*)(hb + (size_t)idx[u] * 128);
        #pragma unroll
        for (int u = 0; u < 8; ++u) accum(v[u]);
    }
    if (e + 4 <= end){
        int idx[4];
        #pragma unroll
        for (int u = 0; u < 4; ++u) idx[u] = esrc[e + u];
        uint4 v[4];
        #pragma unroll
        for (int u = 0; u < 4; ++u) v[u] = *(const uint4*)(hb + (size_t)idx[u] * 128);
        #pragma unroll
        for (int u = 0; u < 4; ++u) accum(v[u]);
        e += 4;
    }
    for (; e < end; ++e){
        uint4 v0 = *(const uint4*)(hb + (size_t)esrc[e] * 128);
        accum(v0);
    }

    u32 o[8];
    #pragma unroll
    for (int k = 0; k < 8; ++k)
        o[k] = (u32)f2bf(acc[k].x * fs) | ((u32)f2bf(acc[k].y * fs) << 16);
    uint4 w0 = {o[0], o[1], o[2], o[3]};
    uint4 w1 = {o[4], o[5], o[6], o[7]};
    *(uint4*)(agg + (size_t)n * 128 + l8 * 16)     = w0;
    *(uint4*)(agg + (size_t)n * 128 + l8 * 16 + 8) = w1;
}

// ------- GEMM: block-cooperative. A tile staged once via global_load_lds
// (k-major [k0][quad][row][16B], linear DMA dest, conflict-free b128 reads).
// 4 waves split output cols. B in registers (AGPR half of the unified file ->
// __launch_bounds__(256,4); do NOT raise: ~128 combined regs, higher bounds spill).
// 3-deep LDS ring, counted vmcnt (4/2/0), raw s_barrier.
// Single C staging buffer (safe: cbuf ds_read completes before the wave's
// global store issues, hence before it can pass the next barrier).
// STATS: binned atomic channel sums (NBIN copies) -> no contention tail.
// AFFA: scale/shift derived from binned sums of the previous layer.
// LSM: log_softmax fused into the store phase (layer 2). -------

template<int NTW, bool STATS, bool AFFA, bool LSM>
__global__ __launch_bounds__(256, 4) void gemm3_kernel(const u16* __restrict__ hA,
                                                       const u16* __restrict__ aggA,
                                                       const u16* __restrict__ Bp,
                                                       const float* __restrict__ bias,
                                                       const float* __restrict__ cs,
                                                       const float* __restrict__ gammaA,
                                                       const float* __restrict__ betaA,
                                                       float invM,
                                                       void* __restrict__ outPre,
                                                       float* __restrict__ csOut,
                                                       int M, int T, int GBs){
    constexpr int N = NTW * 64;                 // output width (4 waves x NTW x 16)
    __shared__ __align__(16) u16 Abuf[3][4096]; // 3 x 8KB A tiles, [k0][quad][row][8 u16]
    __shared__ __align__(16) char cbuf[4352];   // C staging (u16 stride 136 / f32 stride 68)
    __shared__ float s_sc[128], s_sh[128];

    const int wave = threadIdx.x >> 6;
    const int lane = threadIdx.x & 63;
    const int m15 = lane & 15;
    const int quad = lane >> 4;
    const int colbase = wave * (NTW * 16);

    if (AFFA && threadIdx.x < 128){
        const int c = threadIdx.x;
        float s = 0.f, q = 0.f;
        #pragma unroll
        for (int b = 0; b < NBIN; ++b){
            s += cs[b * 256 + c];
            q += cs[b * 256 + 128 + c];
        }
        float mu  = s * invM;
        float var = fmaxf(q * invM - mu * mu, 0.f);
        float sc  = gammaA[c] * rsqrtf(var + 1e-5f);
        s_sc[c] = sc;
        s_sh[c] = betaA[c] - mu * sc;
    }
    __syncthreads();   // once, before any prefetch is in flight

    short8 breg[NTW][8];
    float bv[NTW];
    #pragma unroll
    for (int nt = 0; nt < NTW; ++nt){
        bv[nt] = bias[colbase + nt * 16 + m15];
        #pragma unroll
        for (int k0 = 0; k0 < 8; ++k0)
            breg[nt][k0] = *(const short8*)(Bp + (size_t)(colbase + nt * 16 + m15) * 256 + k0 * 32 + quad * 8);
    }

    float sS[NTW], sQ[NTW];
    #pragma unroll
    for (int nt = 0; nt < NTW; ++nt){ sS[nt] = 0.f; sQ[nt] = 0.f; }

    // wave w stages k0 = 2w, 2w+1 (2 x 1KB DMA per wave per tile)
    auto stage = [&](int bufIdx, int tile){
        const int srow = lane & 15, squad = lane >> 4;
        int arow = tile * 16 + srow;
        if (arow >= M) arow = M - 1;
        #pragma unroll
        for (int h = 0; h < 2; ++h){
            const int k0 = wave * 2 + h;
            const u16* base = (k0 < 4) ? hA : aggA;
            const u16* g = base + (size_t)arow * 128 + (k0 & 3) * 32 + squad * 8;
            gload_lds16(g, &Abuf[bufIdx][k0 * 512]);
        }
    };

    const int t0 = blockIdx.x;
    const int nIter = (T - 1 - t0) / GBs + 1;

    stage(0, t0);
    if (nIter > 1) stage(1, t0 + GBs);

    int t = t0;
    for (int it = 0; it < nIter; ++it){
        const int cur = it % 3;
        if (it + 2 < nIter) stage((it + 2) % 3, t + 2 * GBs);

        const int ahead = min(nIter - 1 - it, 2);
        if (ahead >= 2)      asm volatile("s_waitcnt vmcnt(4)" ::: "memory");
        else if (ahead == 1) asm volatile("s_waitcnt vmcnt(2)" ::: "memory");
        else                 asm volatile("s_waitcnt vmcnt(0)" ::: "memory");
        __builtin_amdgcn_s_barrier();
        __builtin_amdgcn_sched_barrier(0);

        floatx4 acc[NTW];
        #pragma unroll
        for (int nt = 0; nt < NTW; ++nt) acc[nt] = 0.0f;
        #pragma unroll
        for (int k0 = 0; k0 < 8; ++k0){
            short8 a = *(const short8*)&Abuf[cur][k0 * 512 + quad * 128 + m15 * 8];
            if (AFFA && k0 < 4){
                const int cb = k0 * 32 + quad * 8;
                #pragma unroll
                for (int j = 0; j < 8; ++j){
                    float f = bits2f(((u32)(u16)a[j]) << 16);
                    f = fmaxf(fmaf(f, s_sc[cb + j], s_sh[cb + j]), 0.f);
                    a[j] = (short)f2bf(f);
                }
            }
            #pragma unroll
            for (int nt = 0; nt < NTW; ++nt)
                acc[nt] = __builtin_amdgcn_mfma_f32_16x16x32_bf16(a, breg[nt][k0], acc[nt], 0, 0, 0);
        }

        // ---- epilogue: bias (+stats), stage C tile in LDS ----
        const int r0 = quad * 4;
        #pragma unroll
        for (int nt = 0; nt < NTW; ++nt){
            const int col = colbase + nt * 16 + m15;
            #pragma unroll
            for (int r = 0; r < 4; ++r){
                float v = acc[nt][r] + bv[nt];
                if (STATS){
                    int row = t * 16 + r0 + r;
                    if (row < M){
                        sS[nt] += v;
                        sQ[nt] = fmaf(v, v, sQ[nt]);
                    }
                    ((u16*)cbuf)[(r0 + r) * 136 + col] = f2bf(v);
                } else {
                    ((float*)cbuf)[(r0 + r) * 68 + col] = v;
                }
            }
        }
        asm volatile("s_waitcnt lgkmcnt(0)" ::: "memory");
        __builtin_amdgcn_s_barrier();          // C visible; also fences Abuf[cur] reuse
        __builtin_amdgcn_sched_barrier(0);

        const int srow = threadIdx.x >> 4, seg = threadIdx.x & 15;
        const int grow = t * 16 + srow;
        if (LSM){
            // full 64-wide row is held by the 16 threads seg=0..15 of this srow
            float4 w = *(const float4*)((const float*)cbuf + srow * 68 + seg * 4);
            float m = fmaxf(fmaxf(w.x, w.y), fmaxf(w.z, w.w));
            m = fmaxf(m, __shfl_xor(m, 1));
            m = fmaxf(m, __shfl_xor(m, 2));
            m = fmaxf(m, __shfl_xor(m, 4));
            m = fmaxf(m, __shfl_xor(m, 8));
            float e = __expf(w.x - m) + __expf(w.y - m) + __expf(w.z - m) + __expf(w.w - m);
            e += __shfl_xor(e, 1);
            e += __shfl_xor(e, 2);
            e += __shfl_xor(e, 4);
            e += __shfl_xor(e, 8);
            float lg = m + __logf(e);
            if (grow < M){
                float4 o;
                o.x = w.x - lg; o.y = w.y - lg; o.z = w.z - lg; o.w = w.w - lg;
                *(float4*)((float*)outPre + (size_t)grow * 64 + seg * 4) = o;
            }
        } else if (grow < M){
            if (STATS){
                uint4 w = *(const uint4*)((const u16*)cbuf + srow * 136 + seg * 8);
                *(uint4*)((u16*)outPre + (size_t)grow * N + seg * 8) = w;
            } else {
                float4 w = *(const float4*)((const float*)cbuf + srow * 68 + seg * 4);
                *(float4*)((float*)outPre + (size_t)grow * N + seg * 4) = w;
            }
        }
        t += GBs;
    }

    if (STATS){
        const int binoff = (blockIdx.x & (NBIN - 1)) * 256;
        #pragma unroll
        for (int nt = 0; nt < NTW; ++nt){
            float s = sS[nt], q = sQ[nt];
            s += __shfl_xor(s, 16);  s += __shfl_xor(s, 32);
            q += __shfl_xor(q, 16);  q += __shfl_xor(q, 32);
            if (quad == 0){
                const int c = colbase + nt * 16 + m15;
                atomicAdd(&csOut[binoff + c], s);
                atomicAdd(&csOut[binoff + 128 + c], q);
            }
        }
    }
}

// ---------------- host ----------------

extern "C" void kernel_launch(void* const* d_in, const int* in_sizes, int n_in,
                              void* d_out, int out_size, void* d_ws, size_t ws_size,
                              hipStream_t stream) {
    const float* x   = (const float*)d_in[0];
    const int*   src = (const int*)d_in[1];
    const int*   dst = (const int*)d_in[2];
    const float* wself[3]  = {(const float*)d_in[3], (const float*)d_in[6], (const float*)d_in[9]};
    const float* wneigh[3] = {(const float*)d_in[4], (const float*)d_in[7], (const float*)d_in[10]};
    const float* bias[3]   = {(const float*)d_in[5], (const float*)d_in[8], (const float*)d_in[11]};
    const float* gamma[2]  = {(const float*)d_in[12], (const float*)d_in[14]};
    const float* beta[2]   = {(const float*)d_in[13], (const float*)d_in[15]};

    const int M = in_sizes[0] / 128;   // 100000
    const int E = in_sizes[1];         // 1600000
    const int NBUK = (M + 511) / 512;  // 196
    const int T = (M + 15) / 16;       // 6250 A-tiles
    const int GB = 1024;               // proven grid (r7: 381.5us best measured)
    const float invM = 1.0f / (float)M;

    char* ws = (char*)d_ws;
    size_t off = 0;
    auto alloc = [&](size_t bytes) -> void* {
        void* p = ws + off;
        off = (off + bytes + 511) & ~(size_t)511;
        return p;
    };
    // zero-init region first (single memset): gbcnt + binned colstat0/1
    int*   gbcnt    = (int*)alloc(256 * 4);
    float* colstat0 = (float*)alloc(NBIN * 256 * 4);
    float* colstat1 = (float*)alloc(NBIN * 256 * 4);
    const size_t zbytes = off;
    int*   bbase  = (int*)alloc(256 * 4);
    int*   bcur   = (int*)alloc(256 * 4);
    int*   indptr = (int*)alloc((size_t)(M + 1) * 4);
    u32*   pairs  = (u32*)alloc((size_t)E * 4);
    int*   esrc   = (int*)alloc((size_t)E * 4);
    float* invdeg = (float*)alloc((size_t)M * 4);
    u16* bpack0 = (u16*)alloc(128 * 256 * 2);
    u16* bpack1 = (u16*)alloc(128 * 256 * 2);
    u16* bpack2 = (u16*)alloc(64 * 256 * 2);
    u16*   hbuf   = (u16*)alloc((size_t)M * 128 * 2);   // bf16(x)
    u16*   aggbuf = (u16*)alloc((size_t)M * 128 * 2);
    u16*   preA   = (u16*)alloc((size_t)M * 128 * 2);   // layer0 pre-BN (bf16)
    u16*   preB   = (u16*)alloc((size_t)M * 128 * 2);   // layer1 pre-BN (bf16)
    u8*    x8     = (u8*)alloc((size_t)M * 128);        // fp8 gather tables (activated for L1/L2)
    u8*    preA8  = (u8*)alloc((size_t)M * 128);
    u8*    preB8  = (u8*)alloc((size_t)M * 128);

    hipMemsetAsync(ws, 0, zbytes, stream);

    // --- prep (cvt + bhist + pack3 in one launch) ---
    const int nCvtB  = (M * 32 + 255) / 256;   // 12500
    const int nHistB = (E + 8191) / 8192;      // 196
    prep_kernel<<<nCvtB + nHistB + 320, 256, 0, stream>>>(
        x, hbuf, (u32*)x8, M * 32, nCvtB,
        dst, gbcnt, E, nHistB,
        wself[0], wneigh[0], wself[1], wneigh[1], wself[2], wneigh[2],
        bpack0, bpack1, bpack2);

    // --- CSR build ---
    bscan_kernel<<<1, 256, 0, stream>>>(gbcnt, bbase, bcur, NBUK);
    bin_kernel<<<(E + BIN_TILE - 1) / BIN_TILE, 256, 0, stream>>>(src, dst, bcur, pairs, E, NBUK);
    sort2_kernel<<<NBUK, 256, 0, stream>>>(pairs, bbase, indptr, invdeg, esrc, M, E, NBUK);

    // --- layer 0 ---
    agg_kernel<<<(M + 31) / 32, 256, 0, stream>>>(x8, indptr, esrc, invdeg, aggbuf, M);
    gemm3_kernel<2, true, false, false><<<GB, 256, 0, stream>>>(hbuf, aggbuf, bpack0, bias[0],
                                                                nullptr, nullptr, nullptr, invM,
                                                                preA, colstat0, M, T, GB);
    cvt8a_kernel<<<(M * 16 + 255) / 256, 256, 0, stream>>>(preA, colstat0, gamma[0], beta[0], invM,
                                                           (uint2*)preA8, M * 16);

    // --- layer 1 (fp8 table already activated; agg is affine-free) ---
    agg_kernel<<<(M + 31) / 32, 256, 0, stream>>>(preA8, indptr, esrc, invdeg, aggbuf, M);
    gemm3_kernel<2, true, true, false><<<GB, 256, 0, stream>>>(preA, aggbuf, bpack1, bias[1],
                                                               colstat0, gamma[0], beta[0], invM,
                                                               preB, colstat1, M, T, GB);
    cvt8a_kernel<<<(M * 16 + 255) / 256, 256, 0, stream>>>(preB, colstat1, gamma[1], beta[1], invM,
                                                           (uint2*)preB8, M * 16);

    // --- layer 2 (log_softmax fused into gemm epilogue) ---
    agg_kernel<<<(M + 31) / 32, 256, 0, stream>>>(preB8, indptr, esrc, invdeg, aggbuf, M);
    gemm3_kernel<1, false, true, true><<<GB, 256, 0, stream>>>(preB, aggbuf, bpack2, bias[2],
                                                               colstat1, gamma[1], beta[1], invM,
                                                               d_out, nullptr, M, T, GB);
}